// Round 2
// baseline (364.995 us; speedup 1.0000x reference)
//
#include <hip/hip_runtime.h>

typedef unsigned short u16;
typedef __bf16 bf16x8 __attribute__((ext_vector_type(8)));
typedef float  fx4    __attribute__((ext_vector_type(4)));

__device__ __forceinline__ u16 f2bf(float f) {
    unsigned int x = __builtin_bit_cast(unsigned int, f);
    x = x + 0x7fffu + ((x >> 16) & 1u);   // round-to-nearest-even
    return (u16)(x >> 16);
}
__device__ __forceinline__ __bf16 f2bf16(float f) {
    return __builtin_bit_cast(__bf16, f2bf(f));
}

#define MFMA16(a, b, c) __builtin_amdgcn_mfma_f32_16x16x32_bf16((a), (b), (c), 0, 0, 0)

// ---------------------------------------------------------------------------
// Kernel 1: q/k/v = X @ W + b   (fp32 in -> bf16 MFMA, fp32 acc, bf16 out ws)
// 256 blocks x 256 threads; each wave computes 16 rows x 128 cols x 3 proj.
// ---------------------------------------------------------------------------
__global__ __launch_bounds__(256) void qkv_kernel(
    const float* __restrict__ X,
    const float* __restrict__ Wq, const float* __restrict__ bq,
    const float* __restrict__ Wk, const float* __restrict__ bk,
    const float* __restrict__ Wv, const float* __restrict__ bv,
    u16* __restrict__ qo, u16* __restrict__ ko, u16* __restrict__ vo)
{
    const int tid  = threadIdx.x;
    const int w    = tid >> 6;
    const int lane = tid & 63;
    const int n    = lane & 15;
    const int quad = lane >> 4;
    const int row0 = blockIdx.x * 64 + w * 16;

    // A fragments: X[row0 + n][k], k = kk*32 + quad*8 + j  (fp32 -> bf16)
    bf16x8 af[4];
    {
        const float* xr = X + (size_t)(row0 + n) * 128;
#pragma unroll
        for (int kk = 0; kk < 4; ++kk) {
            float4 f0 = *(const float4*)(xr + kk * 32 + quad * 8);
            float4 f1 = *(const float4*)(xr + kk * 32 + quad * 8 + 4);
            bf16x8 a;
            a[0] = f2bf16(f0.x); a[1] = f2bf16(f0.y); a[2] = f2bf16(f0.z); a[3] = f2bf16(f0.w);
            a[4] = f2bf16(f1.x); a[5] = f2bf16(f1.y); a[6] = f2bf16(f1.z); a[7] = f2bf16(f1.w);
            af[kk] = a;
        }
    }

    const float* Ws[3] = {Wq, Wk, Wv};
    const float* Bs[3] = {bq, bk, bv};
    u16*         Os[3] = {qo, ko, vo};

#pragma unroll
    for (int p = 0; p < 3; ++p) {
        const float* W = Ws[p];
#pragma unroll
        for (int nt = 0; nt < 8; ++nt) {
            fx4 acc = {0.f, 0.f, 0.f, 0.f};
#pragma unroll
            for (int kk = 0; kk < 4; ++kk) {
                // B fragment: W[k = kk*32 + quad*8 + j][col = nt*16 + n]
                const float* wp = W + (size_t)(kk * 32 + quad * 8) * 128 + nt * 16 + n;
                bf16x8 bf;
#pragma unroll
                for (int j = 0; j < 8; ++j)
                    bf[j] = f2bf16(wp[j * 128]);
                acc = MFMA16(af[kk], bf, acc);
            }
            const float bb = Bs[p][nt * 16 + n];
#pragma unroll
            for (int r = 0; r < 4; ++r) {
                // C layout: row = quad*4 + r, col = nt*16 + n
                Os[p][(size_t)(row0 + quad * 4 + r) * 128 + nt * 16 + n] = f2bf(acc[r] + bb);
            }
        }
    }
}

// ---------------------------------------------------------------------------
// Kernel 2: fused masked attention, flash-style online softmax, MFMA.
// 256 blocks (8 batches x 32 q-tiles of 64), 4 waves, 16 queries per wave.
// ---------------------------------------------------------------------------
__global__ __launch_bounds__(256) void attn_kernel(
    const u16* __restrict__ Q, const u16* __restrict__ Kp,
    const u16* __restrict__ Vp, const int* __restrict__ adj,
    float* __restrict__ out)
{
    __shared__ __align__(16) u16 kt[32 * 136];   // K tile, padded stride
    __shared__ __align__(16) u16 vt[128 * 40];   // V tile transposed [d][key]
    __shared__ __align__(16) u16 pl[4 * 16 * 40];// P per wave [16 q][32 k], stride 40

    const int tid  = threadIdx.x;
    const int w    = tid >> 6;
    const int lane = tid & 63;
    const int n    = lane & 15;
    const int quad = lane >> 4;
    const int b    = blockIdx.x >> 5;
    const int qt   = blockIdx.x & 31;
    const int q0   = qt * 64 + w * 16;

    // Q fragments in registers (A-layout): Q[q0 + n][kk*32 + quad*8 + j]
    bf16x8 qf[4];
    {
        const u16* qr = Q + (size_t)(b * 2048 + q0 + n) * 128;
#pragma unroll
        for (int kk = 0; kk < 4; ++kk)
            qf[kk] = __builtin_bit_cast(bf16x8, *(const uint4*)(qr + kk * 32 + quad * 8));
    }

    fx4 O[8];
#pragma unroll
    for (int i = 0; i < 8; ++i) O[i] = (fx4){0.f, 0.f, 0.f, 0.f};
    float m_r[4] = {-1e30f, -1e30f, -1e30f, -1e30f};
    float l_r[4] = {0.f, 0.f, 0.f, 0.f};

    const float SCALE = 0.08838834764831845f;  // 1/sqrt(128)
    u16* pw = &pl[w * 640];

    for (int t = 0; t < 64; ++t) {
        const int k0 = t * 32;
        __syncthreads();  // protect kt/vt from previous iteration's readers
        // ---- stage K tile: [32 keys][128 d] -> kt stride 136
        {
            const int r = tid >> 3, c = (tid & 7) * 16;
            const u16* src = Kp + (size_t)(b * 2048 + k0 + r) * 128 + c;
            *(uint4*)&kt[r * 136 + c]     = *(const uint4*)src;
            *(uint4*)&kt[r * 136 + c + 8] = *(const uint4*)(src + 8);
        }
        // ---- stage V tile transposed: vt[d][key], stride 40
        {
            const int key = tid & 31, d0 = (tid >> 5) * 16;
            const u16* src = Vp + (size_t)(b * 2048 + k0 + key) * 128 + d0;
            uint4 u0 = *(const uint4*)src;
            uint4 u1 = *(const uint4*)(src + 8);
#define PUT2(word, dbase) { vt[(dbase) * 40 + key]     = (u16)((word) & 0xffffu); \
                            vt[((dbase) + 1) * 40 + key] = (u16)((word) >> 16); }
            PUT2(u0.x, d0 + 0)  PUT2(u0.y, d0 + 2)  PUT2(u0.z, d0 + 4)  PUT2(u0.w, d0 + 6)
            PUT2(u1.x, d0 + 8)  PUT2(u1.y, d0 + 10) PUT2(u1.z, d0 + 12) PUT2(u1.w, d0 + 14)
#undef PUT2
        }
        __syncthreads();

        // ---- S = Q K^T  (two 16x16 score tiles, keys [k0, k0+32))
        fx4 S0 = {0.f, 0.f, 0.f, 0.f}, S1 = {0.f, 0.f, 0.f, 0.f};
#pragma unroll
        for (int kk = 0; kk < 4; ++kk) {
            bf16x8 kb0 = __builtin_bit_cast(bf16x8, *(const uint4*)&kt[n * 136 + kk * 32 + quad * 8]);
            bf16x8 kb1 = __builtin_bit_cast(bf16x8, *(const uint4*)&kt[(n + 16) * 136 + kk * 32 + quad * 8]);
            S0 = MFMA16(qf[kk], kb0, S0);
            S1 = MFMA16(qf[kk], kb1, S1);
        }

        // ---- scale + adjacency bias (C layout: row = quad*4+r, col = key)
        float s0[4], s1[4];
#pragma unroll
        for (int r = 0; r < 4; ++r) {
            const int row = b * 2048 + q0 + quad * 4 + r;
            const int* ap = adj + (size_t)row * 2048 + k0;
            s0[r] = S0[r] * SCALE + (ap[n]      ? 0.f : -10000.f);
            s1[r] = S1[r] * SCALE + (ap[16 + n] ? 0.f : -10000.f);
        }

        // ---- online softmax: row max over 32 keys (reduce across 16 lanes)
        float alpha[4];
#pragma unroll
        for (int r = 0; r < 4; ++r) {
            float x = fmaxf(s0[r], s1[r]);
#pragma unroll
            for (int off = 1; off < 16; off <<= 1) x = fmaxf(x, __shfl_xor(x, off));
            const float mn = fmaxf(m_r[r], x);
            alpha[r] = __expf(m_r[r] - mn);
            m_r[r] = mn;
        }
        // p = exp(s - m), write to LDS (bf16), accumulate l from rounded p
#pragma unroll
        for (int r = 0; r < 4; ++r) {
            const float p0 = __expf(s0[r] - m_r[r]);
            const float p1 = __expf(s1[r] - m_r[r]);
            const u16 ub0 = f2bf(p0), ub1 = f2bf(p1);
            pw[(quad * 4 + r) * 40 + n]      = ub0;
            pw[(quad * 4 + r) * 40 + 16 + n] = ub1;
            unsigned int lo = ((unsigned int)ub0) << 16, hi = ((unsigned int)ub1) << 16;
            float ps = __builtin_bit_cast(float, lo) + __builtin_bit_cast(float, hi);
#pragma unroll
            for (int off = 1; off < 16; off <<= 1) ps += __shfl_xor(ps, off);
            l_r[r] = l_r[r] * alpha[r] + ps;
        }
        // rescale accumulator
#pragma unroll
        for (int i = 0; i < 8; ++i) {
#pragma unroll
            for (int r = 0; r < 4; ++r) O[i][r] *= alpha[r];
        }
        __syncthreads();  // make P visible (cross-lane LDS round-trip)

        // ---- O += P V   (A = P from LDS in A-layout, B = V^T tile)
        bf16x8 pf = __builtin_bit_cast(bf16x8, *(const uint4*)&pw[n * 40 + quad * 8]);
#pragma unroll
        for (int dt = 0; dt < 8; ++dt) {
            bf16x8 vf = __builtin_bit_cast(bf16x8, *(const uint4*)&vt[(dt * 16 + n) * 40 + quad * 8]);
            O[dt] = MFMA16(pf, vf, O[dt]);
        }
    }

    // ---- epilogue: h = O / l, elu, store fp32
#pragma unroll
    for (int dt = 0; dt < 8; ++dt) {
#pragma unroll
        for (int r = 0; r < 4; ++r) {
            const float h = O[dt][r] / l_r[r];
            const float e = (h > 0.f) ? h : (__expf(h) - 1.f);
            out[(size_t)(b * 2048 + q0 + quad * 4 + r) * 128 + dt * 16 + n] = e;
        }
    }
}

// ---------------------------------------------------------------------------
extern "C" void kernel_launch(void* const* d_in, const int* in_sizes, int n_in,
                              void* d_out, int out_size, void* d_ws, size_t ws_size,
                              hipStream_t stream) {
    (void)in_sizes; (void)n_in; (void)out_size; (void)ws_size;
    const float* X   = (const float*)d_in[0];
    const int*   adj = (const int*)d_in[1];
    const float* Wq  = (const float*)d_in[2];
    const float* bq  = (const float*)d_in[3];
    const float* Wk  = (const float*)d_in[4];
    const float* bk  = (const float*)d_in[5];
    const float* Wv  = (const float*)d_in[6];
    const float* bv  = (const float*)d_in[7];
    float* out = (float*)d_out;

    u16* qws = (u16*)d_ws;                       // 16384*128 bf16 = 4 MB
    u16* kws = qws + (size_t)16384 * 128;        // 4 MB
    u16* vws = kws + (size_t)16384 * 128;        // 4 MB  (needs ws >= 12 MB)

    qkv_kernel<<<256, 256, 0, stream>>>(X, Wq, bq, Wk, bk, Wv, bv, qws, kws, vws);
    attn_kernel<<<256, 256, 0, stream>>>(qws, kws, vws, adj, out);
}

// Round 3
// 325.453 us; speedup vs baseline: 1.1215x; 1.1215x over previous
//
#include <hip/hip_runtime.h>

typedef unsigned short u16;
typedef __bf16 bf16x8 __attribute__((ext_vector_type(8)));
typedef float  fx4    __attribute__((ext_vector_type(4)));

__device__ __forceinline__ u16 f2bf(float f) {
    unsigned int x = __builtin_bit_cast(unsigned int, f);
    x = x + 0x7fffu + ((x >> 16) & 1u);   // round-to-nearest-even
    return (u16)(x >> 16);
}
__device__ __forceinline__ __bf16 f2bf16(float f) {
    return __builtin_bit_cast(__bf16, f2bf(f));
}
__device__ __forceinline__ float bfbits2f(u16 u) {
    unsigned int x = ((unsigned int)u) << 16;
    return __builtin_bit_cast(float, x);
}

#define MFMA16(a, b, c) __builtin_amdgcn_mfma_f32_16x16x32_bf16((a), (b), (c), 0, 0, 0)
// wave-private LDS write->read ordering (DS ops are in-order per wave)
#define WAVE_LDS_SYNC() __asm__ volatile("s_waitcnt lgkmcnt(0)" ::: "memory")

// ---------------------------------------------------------------------------
// Kernel A: WT[p][c][k] = bf16(W_p[k][c])  -> stored in first 96 KB of d_out
// ---------------------------------------------------------------------------
__global__ __launch_bounds__(256) void wt_kernel(
    const float* __restrict__ Wq, const float* __restrict__ Wk,
    const float* __restrict__ Wv, u16* __restrict__ WT)
{
    const int o = blockIdx.x * 256 + threadIdx.x;     // 0..49151
    const int p = o >> 14, rem = o & 16383, c = rem >> 7, k = rem & 127;
    const float* W = (p == 0) ? Wq : ((p == 1) ? Wk : Wv);
    WT[o] = f2bf(W[k * 128 + c]);
}

// ---------------------------------------------------------------------------
// Kernel B: q/k/v = X @ W + b. 512 blocks x 256 thr; wave = (row-tile, col-half)
// B-fragments are vector loads from the bf16 W^T table (L2-resident).
// ---------------------------------------------------------------------------
__global__ __launch_bounds__(256) void qkv_kernel(
    const float* __restrict__ X, const u16* __restrict__ WT,
    const float* __restrict__ bq, const float* __restrict__ bk,
    const float* __restrict__ bv,
    u16* __restrict__ qo, u16* __restrict__ ko, u16* __restrict__ vo)
{
    const int tid  = threadIdx.x;
    const int w    = tid >> 6;
    const int lane = tid & 63;
    const int n    = lane & 15;
    const int quad = lane >> 4;
    const int gw   = blockIdx.x * 4 + w;   // 0..2047
    const int rt   = gw >> 1, ch = gw & 1;
    const int row0 = rt * 16;

    // A fragments: X[row0+n][kk*32 + quad*8 + j]  fp32 -> bf16
    bf16x8 af[4];
    {
        const float* xr = X + (size_t)(row0 + n) * 128;
#pragma unroll
        for (int kk = 0; kk < 4; ++kk) {
            float4 f0 = *(const float4*)(xr + kk * 32 + quad * 8);
            float4 f1 = *(const float4*)(xr + kk * 32 + quad * 8 + 4);
            bf16x8 a;
            a[0] = f2bf16(f0.x); a[1] = f2bf16(f0.y); a[2] = f2bf16(f0.z); a[3] = f2bf16(f0.w);
            a[4] = f2bf16(f1.x); a[5] = f2bf16(f1.y); a[6] = f2bf16(f1.z); a[7] = f2bf16(f1.w);
            af[kk] = a;
        }
    }

    const float* Bs[3] = {bq, bk, bv};
    u16*         Os[3] = {qo, ko, vo};

#pragma unroll
    for (int p = 0; p < 3; ++p) {
        const u16* wt = WT + p * 16384;
#pragma unroll
        for (int nt = 0; nt < 4; ++nt) {
            const int col0 = ch * 64 + nt * 16;
            fx4 acc = {0.f, 0.f, 0.f, 0.f};
#pragma unroll
            for (int kk = 0; kk < 4; ++kk) {
                bf16x8 bf = __builtin_bit_cast(bf16x8,
                    *(const uint4*)&wt[(col0 + n) * 128 + kk * 32 + quad * 8]);
                acc = MFMA16(af[kk], bf, acc);
            }
            const float bb = Bs[p][col0 + n];
#pragma unroll
            for (int r = 0; r < 4; ++r)
                Os[p][(size_t)(row0 + quad * 4 + r) * 128 + col0 + n] = f2bf(acc[r] + bb);
        }
    }
}

// ---------------------------------------------------------------------------
// Kernel C: fused masked attention. 512 blocks x 256 thr (8 batch x 64 qtiles
// of 32 q). 4 waves = 2 q-tiles x 2 key-halves over 64-key mega-tiles.
// Double-buffered K/V staging; adj prefetched one iteration ahead; one
// __syncthreads per iteration; LDS merge of the 2-way key split at the end.
// ---------------------------------------------------------------------------
__global__ __launch_bounds__(256, 2) void attn_kernel(
    const u16* __restrict__ Q, const u16* __restrict__ Kp,
    const u16* __restrict__ Vp, const int* __restrict__ adj,
    float* __restrict__ out)
{
    __shared__ __align__(16) char smem[71680];       // staging / merge union
    __shared__ __align__(16) u16 pl[4][640];         // per-wave P, stride 40
    u16* ktb = (u16*)smem;                           // [2][64*136]
    u16* vtb = (u16*)(smem + 34816);                 // [2][128*72]

    const int tid  = threadIdx.x;
    const int w    = tid >> 6;
    const int lane = tid & 63;
    const int n    = lane & 15;
    const int quad = lane >> 4;
    const int b    = blockIdx.x & 7;                 // batch -> XCD pinning
    const int qt   = blockIdx.x >> 3;                // 0..63
    const int qi   = w >> 1;                         // q-tile in block (0..1)
    const int h    = w & 1;                          // key-half (0..1)
    const int q0   = qt * 32 + qi * 16;
    const size_t bN = (size_t)b * 2048;

    // staging roles (all 256 threads)
    const int kr = tid >> 2, kc = (tid & 3) * 32;    // K: 64 rows x 128 cols
    const int vk = lane;                              // V key index
    const int vd0 = w * 32;                           // V d-slice per wave

    // Q fragments (A-layout), resident
    bf16x8 qf[4];
    {
        const u16* qr = Q + (bN + q0 + n) * 128;
#pragma unroll
        for (int kk = 0; kk < 4; ++kk)
            qf[kk] = __builtin_bit_cast(bf16x8, *(const uint4*)(qr + kk * 32 + quad * 8));
    }

    fx4 O[8];
#pragma unroll
    for (int i = 0; i < 8; ++i) O[i] = (fx4){0.f, 0.f, 0.f, 0.f};
    float m_r[4] = {-1e30f, -1e30f, -1e30f, -1e30f};
    float l_r[4] = {0.f, 0.f, 0.f, 0.f};

    const int* adjr[4];
#pragma unroll
    for (int r = 0; r < 4; ++r) adjr[r] = adj + (bN + q0 + quad * 4 + r) * 2048;

    // ---- prologue: stage tile 0 into buf0; adj tile 0 into regs
    {
        const u16* ks = Kp + (bN + kr) * 128 + kc;
#pragma unroll
        for (int i = 0; i < 4; ++i)
            *(uint4*)&ktb[kr * 136 + kc + i * 8] = *(const uint4*)(ks + i * 8);
        const u16* vs = Vp + (bN + vk) * 128 + vd0;
#pragma unroll
        for (int i = 0; i < 4; ++i) {
            union { uint4 q; u16 e[8]; } tv; tv.q = *(const uint4*)(vs + i * 8);
#pragma unroll
            for (int j = 0; j < 8; ++j) vtb[(vd0 + i * 8 + j) * 72 + vk] = tv.e[j];
        }
    }
    int a0c[4], a1c[4];
#pragma unroll
    for (int r = 0; r < 4; ++r) {
        a0c[r] = adjr[r][h * 32 + n];
        a1c[r] = adjr[r][h * 32 + 16 + n];
    }

    const float SCALE = 0.08838834764831845f;  // 1/sqrt(128)
    u16* pw = pl[w];

    for (int t = 0; t < 32; ++t) {
        __syncthreads();                        // buf[t&1] + prev writes visible
        const int cur = t & 1;
        const u16* ktc = ktb + cur * 8704;
        const u16* vtc = vtb + cur * 9216;

        // ---- issue prefetch for tile t+1 (overlaps entire compute below)
        uint4 kreg[4], vreg[4];
        int a0n[4], a1n[4];
        if (t < 31) {
            const int k0 = (t + 1) * 64;
            const u16* ks = Kp + (bN + k0 + kr) * 128 + kc;
#pragma unroll
            for (int i = 0; i < 4; ++i) kreg[i] = *(const uint4*)(ks + i * 8);
            const u16* vs = Vp + (bN + k0 + vk) * 128 + vd0;
#pragma unroll
            for (int i = 0; i < 4; ++i) vreg[i] = *(const uint4*)(vs + i * 8);
#pragma unroll
            for (int r = 0; r < 4; ++r) {
                a0n[r] = adjr[r][k0 + h * 32 + n];
                a1n[r] = adjr[r][k0 + h * 32 + 16 + n];
            }
        }

        // ---- S = Q K^T  (keys [t*64 + h*32, +32))
        fx4 S0 = {0.f, 0.f, 0.f, 0.f}, S1 = {0.f, 0.f, 0.f, 0.f};
#pragma unroll
        for (int kk = 0; kk < 4; ++kk) {
            bf16x8 kb0 = __builtin_bit_cast(bf16x8,
                *(const uint4*)&ktc[(h * 32 + n) * 136 + kk * 32 + quad * 8]);
            bf16x8 kb1 = __builtin_bit_cast(bf16x8,
                *(const uint4*)&ktc[(h * 32 + 16 + n) * 136 + kk * 32 + quad * 8]);
            S0 = MFMA16(qf[kk], kb0, S0);
            S1 = MFMA16(qf[kk], kb1, S1);
        }

        // ---- online softmax (adj from regs prefetched last iter)
        float alpha[4];
#pragma unroll
        for (int r = 0; r < 4; ++r) {
            const float s0 = S0[r] * SCALE + (a0c[r] ? 0.f : -10000.f);
            const float s1 = S1[r] * SCALE + (a1c[r] ? 0.f : -10000.f);
            float x = fmaxf(s0, s1);
#pragma unroll
            for (int off = 1; off < 16; off <<= 1) x = fmaxf(x, __shfl_xor(x, off));
            const float mn = fmaxf(m_r[r], x);
            alpha[r] = __expf(m_r[r] - mn);
            m_r[r] = mn;
            const float p0 = __expf(s0 - mn);
            const float p1 = __expf(s1 - mn);
            const u16 ub0 = f2bf(p0), ub1 = f2bf(p1);
            pw[(quad * 4 + r) * 40 + n]      = ub0;
            pw[(quad * 4 + r) * 40 + 16 + n] = ub1;
            float ps = bfbits2f(ub0) + bfbits2f(ub1);
#pragma unroll
            for (int off = 1; off < 16; off <<= 1) ps += __shfl_xor(ps, off);
            l_r[r] = l_r[r] * alpha[r] + ps;
        }
#pragma unroll
        for (int i = 0; i < 8; ++i) {
#pragma unroll
            for (int r = 0; r < 4; ++r) O[i][r] *= alpha[r];
        }
        WAVE_LDS_SYNC();   // pl write -> read, wave-private

        // ---- O += P V
        bf16x8 pf = __builtin_bit_cast(bf16x8, *(const uint4*)&pw[n * 40 + quad * 8]);
#pragma unroll
        for (int dt = 0; dt < 8; ++dt) {
            bf16x8 vf = __builtin_bit_cast(bf16x8,
                *(const uint4*)&vtc[(dt * 16 + n) * 72 + h * 32 + quad * 8]);
            O[dt] = MFMA16(pf, vf, O[dt]);
        }

        // ---- drain prefetch into the other buffer
        if (t < 31) {
            u16* ktn = ktb + (cur ^ 1) * 8704;
            u16* vtn = vtb + (cur ^ 1) * 9216;
#pragma unroll
            for (int i = 0; i < 4; ++i)
                *(uint4*)&ktn[kr * 136 + kc + i * 8] = kreg[i];
#pragma unroll
            for (int i = 0; i < 4; ++i) {
                union { uint4 q; u16 e[8]; } tv; tv.q = vreg[i];
#pragma unroll
                for (int j = 0; j < 8; ++j) vtn[(vd0 + i * 8 + j) * 72 + vk] = tv.e[j];
            }
#pragma unroll
            for (int r = 0; r < 4; ++r) { a0c[r] = a0n[r]; a1c[r] = a1n[r]; }
        }
    }

    // ---- merge the two key-halves (reuse staging LDS), ELU, store
    __syncthreads();
    float* mO  = (float*)smem;            // [2][16][128]
    float* mml = (float*)(smem + 16384);  // [2]{m[16], l[16]}
    if (h == 1) {
#pragma unroll
        for (int r = 0; r < 4; ++r) {
            if (n == 0) {
                mml[qi * 32 + quad * 4 + r]      = m_r[r];
                mml[qi * 32 + 16 + quad * 4 + r] = l_r[r];
            }
#pragma unroll
            for (int dt = 0; dt < 8; ++dt)
                mO[(qi * 16 + quad * 4 + r) * 128 + dt * 16 + n] = O[dt][r];
        }
    }
    __syncthreads();
    if (h == 0) {
#pragma unroll
        for (int r = 0; r < 4; ++r) {
            const float m1 = mml[qi * 32 + quad * 4 + r];
            const float l1 = mml[qi * 32 + 16 + quad * 4 + r];
            const float M  = fmaxf(m_r[r], m1);
            const float a0 = __expf(m_r[r] - M), a1 = __expf(m1 - M);
            const float linv = 1.f / (l_r[r] * a0 + l1 * a1);
            float* po = out + (bN + q0 + quad * 4 + r) * 128;
            const float* o1 = &mO[(qi * 16 + quad * 4 + r) * 128];
#pragma unroll
            for (int dt = 0; dt < 8; ++dt) {
                const float hh = (O[dt][r] * a0 + o1[dt * 16 + n] * a1) * linv;
                po[dt * 16 + n] = (hh > 0.f) ? hh : (__expf(hh) - 1.f);
            }
        }
    }
}

// ---------------------------------------------------------------------------
extern "C" void kernel_launch(void* const* d_in, const int* in_sizes, int n_in,
                              void* d_out, int out_size, void* d_ws, size_t ws_size,
                              hipStream_t stream) {
    (void)in_sizes; (void)n_in; (void)out_size; (void)ws_size;
    const float* X   = (const float*)d_in[0];
    const int*   adj = (const int*)d_in[1];
    const float* Wq  = (const float*)d_in[2];
    const float* bq  = (const float*)d_in[3];
    const float* Wk  = (const float*)d_in[4];
    const float* bk  = (const float*)d_in[5];
    const float* Wv  = (const float*)d_in[6];
    const float* bv  = (const float*)d_in[7];
    float* out = (float*)d_out;

    u16* WT  = (u16*)d_out;                      // 96 KB scratch, overwritten by attn
    u16* qws = (u16*)d_ws;                       // 4 MB
    u16* kws = qws + (size_t)16384 * 128;        // 4 MB
    u16* vws = kws + (size_t)16384 * 128;        // 4 MB

    wt_kernel<<<192, 256, 0, stream>>>(Wq, Wk, Wv, WT);
    qkv_kernel<<<512, 256, 0, stream>>>(X, WT, bq, bk, bv, qws, kws, vws);
    attn_kernel<<<512, 256, 0, stream>>>(qws, kws, vws, adj, out);
}

// Round 4
// 323.858 us; speedup vs baseline: 1.1270x; 1.0049x over previous
//
#include <hip/hip_runtime.h>

typedef unsigned short u16;
typedef __bf16 bf16x8 __attribute__((ext_vector_type(8)));
typedef float  fx4    __attribute__((ext_vector_type(4)));

__device__ __forceinline__ u16 f2bf(float f) {
    unsigned int x = __builtin_bit_cast(unsigned int, f);
    x = x + 0x7fffu + ((x >> 16) & 1u);   // round-to-nearest-even
    return (u16)(x >> 16);
}
__device__ __forceinline__ __bf16 f2bf16(float f) {
    return __builtin_bit_cast(__bf16, f2bf(f));
}
__device__ __forceinline__ float bfbits2f(u16 u) {
    unsigned int x = ((unsigned int)u) << 16;
    return __builtin_bit_cast(float, x);
}

#define MFMA16(a, b, c) __builtin_amdgcn_mfma_f32_16x16x32_bf16((a), (b), (c), 0, 0, 0)
// wave-private LDS write->read ordering (DS ops are in-order per wave)
#define WAVE_LDS_SYNC() __asm__ volatile("s_waitcnt lgkmcnt(0)" ::: "memory")

// ---------------------------------------------------------------------------
// Kernel A: WT[p][c][k] = bf16(W_p[k][c])  -> stored in first 96 KB of d_out
// ---------------------------------------------------------------------------
__global__ __launch_bounds__(256) void wt_kernel(
    const float* __restrict__ Wq, const float* __restrict__ Wk,
    const float* __restrict__ Wv, u16* __restrict__ WT)
{
    const int o = blockIdx.x * 256 + threadIdx.x;     // 0..49151
    const int p = o >> 14, rem = o & 16383, c = rem >> 7, k = rem & 127;
    const float* W = (p == 0) ? Wq : ((p == 1) ? Wk : Wv);
    WT[o] = f2bf(W[k * 128 + c]);
}

// ---------------------------------------------------------------------------
// Kernel B: q/k = X @ W + b  ([key][d] bf16);  vT = (X @ Wv + bv)^T  ([d][key])
// computed directly via operand-swapped MFMA (A = Wv^T from WT, B = X frags).
// 512 blocks x 256 thr; wave = (row-tile of 16, col/d half of 64).
// ---------------------------------------------------------------------------
__global__ __launch_bounds__(256, 2) void qkv_kernel(
    const float* __restrict__ X, const u16* __restrict__ WT,
    const float* __restrict__ bq, const float* __restrict__ bk,
    const float* __restrict__ bv,
    u16* __restrict__ qo, u16* __restrict__ ko, u16* __restrict__ vto)
{
    const int tid  = threadIdx.x;
    const int w    = tid >> 6;
    const int lane = tid & 63;
    const int n    = lane & 15;
    const int quad = lane >> 4;
    const int gw   = blockIdx.x * 4 + w;   // 0..2047
    const int rt   = gw >> 1, ch = gw & 1;
    const int row0 = rt * 16;

    // X fragments: lane holds X[row0+n][kk*32 + quad*8 + j]  (fp32 -> bf16).
    // Serves as MFMA A-operand for Q/K and as B-operand for V^T.
    bf16x8 af[4];
    {
        const float* xr = X + (size_t)(row0 + n) * 128;
#pragma unroll
        for (int kk = 0; kk < 4; ++kk) {
            float4 f0 = *(const float4*)(xr + kk * 32 + quad * 8);
            float4 f1 = *(const float4*)(xr + kk * 32 + quad * 8 + 4);
            bf16x8 a;
            a[0] = f2bf16(f0.x); a[1] = f2bf16(f0.y); a[2] = f2bf16(f0.z); a[3] = f2bf16(f0.w);
            a[4] = f2bf16(f1.x); a[5] = f2bf16(f1.y); a[6] = f2bf16(f1.z); a[7] = f2bf16(f1.w);
            af[kk] = a;
        }
    }

    // ---- Q and K, direct layout [key][d]
    const float* Bs[2] = {bq, bk};
    u16*         Os[2] = {qo, ko};
#pragma unroll
    for (int p = 0; p < 2; ++p) {
        const u16* wt = WT + p * 16384;
#pragma unroll
        for (int nt = 0; nt < 4; ++nt) {
            const int col0 = ch * 64 + nt * 16;
            fx4 acc = {0.f, 0.f, 0.f, 0.f};
#pragma unroll
            for (int kk = 0; kk < 4; ++kk) {
                bf16x8 bf = __builtin_bit_cast(bf16x8,
                    *(const uint4*)&wt[(col0 + n) * 128 + kk * 32 + quad * 8]);
                acc = MFMA16(af[kk], bf, acc);
            }
            const float bb = Bs[p][col0 + n];
#pragma unroll
            for (int r = 0; r < 4; ++r)
                Os[p][(size_t)(row0 + quad * 4 + r) * 128 + col0 + n] = f2bf(acc[r] + bb);
        }
    }

    // ---- V^T[d][key] = sum_k Wv^T[d][k] * X^T[k][key]
    {
        const u16* wtv = WT + 2 * 16384;
        const int b = row0 >> 11;
        const int keyloc = (row0 & 2047) + n;   // C col = n = key offset
        u16* vb = vto + (size_t)b * 262144;     // 128*2048 per batch
#pragma unroll
        for (int d0 = 0; d0 < 4; ++d0) {
            const int dbase = ch * 64 + d0 * 16;
            fx4 acc = {0.f, 0.f, 0.f, 0.f};
#pragma unroll
            for (int kk = 0; kk < 4; ++kk) {
                // A[m=d][k]: lane m=n reads Wv^T row (dbase+n)
                bf16x8 wf = __builtin_bit_cast(bf16x8,
                    *(const uint4*)&wtv[(dbase + n) * 128 + kk * 32 + quad * 8]);
                acc = MFMA16(wf, af[kk], acc);
            }
#pragma unroll
            for (int r = 0; r < 4; ++r) {
                const int d = dbase + quad * 4 + r;
                vb[(size_t)d * 2048 + keyloc] = f2bf(acc[r] + bv[d]);
            }
        }
    }
}

// ---------------------------------------------------------------------------
// Kernel C: fused masked attention, NO in-loop barriers.
// 1024 blocks (128 q-tiles x 8 batches, b = blockIdx&7 for XCD pinning).
// 4 waves per block = 4 key-quarters of one 16-query tile; each wave streams
// 16 x 32-key tiles reading K/V MFMA fragments DIRECTLY from L2-resident
// workspace (single uint4 per fragment). One barrier at the 4-way merge.
// ---------------------------------------------------------------------------
__global__ __launch_bounds__(256, 4) void attn_kernel(
    const u16* __restrict__ Q, const u16* __restrict__ Kp,
    const u16* __restrict__ vT, const int* __restrict__ adj,
    float* __restrict__ out)
{
    __shared__ __align__(16) float mO[4][16 * 128];  // per-wave O dump (32 KB)
    __shared__ __align__(16) float mml[4][32];       // per-wave m[16], l[16]
    __shared__ __align__(16) u16 pl[4][640];         // per-wave P, stride 40

    const int tid  = threadIdx.x;
    const int h    = tid >> 6;                       // key-quarter
    const int lane = tid & 63;
    const int n    = lane & 15;
    const int quad = lane >> 4;
    const int b    = blockIdx.x & 7;
    const int qt   = blockIdx.x >> 3;                // 0..127
    const int q0   = qt * 16;
    const size_t bN = (size_t)b * 2048;
    const u16* vTb = vT + (size_t)b * 262144 + n * 2048 + quad * 8;

    // Q fragments (A-layout), resident
    bf16x8 qf[4];
    {
        const u16* qr = Q + (bN + q0 + n) * 128;
#pragma unroll
        for (int kk = 0; kk < 4; ++kk)
            qf[kk] = __builtin_bit_cast(bf16x8, *(const uint4*)(qr + kk * 32 + quad * 8));
    }

    fx4 O[8];
#pragma unroll
    for (int i = 0; i < 8; ++i) O[i] = (fx4){0.f, 0.f, 0.f, 0.f};
    float m_r[4] = {-1e30f, -1e30f, -1e30f, -1e30f};
    float l_r[4] = {0.f, 0.f, 0.f, 0.f};

    const int* adjb = adj + (bN + q0 + quad * 4) * 2048;
    const float SCALE = 0.08838834764831845f;  // 1/sqrt(128)
    u16* pw = pl[h];

    for (int t = 0; t < 16; ++t) {
        const int k0 = h * 512 + t * 32;

        // ---- adjacency (HBM): issue first, used after QK^T
        int a0[4], a1[4];
#pragma unroll
        for (int r = 0; r < 4; ++r) {
            a0[r] = adjb[(size_t)r * 2048 + k0 + n];
            a1[r] = adjb[(size_t)r * 2048 + k0 + 16 + n];
        }

        // ---- K fragments straight from L2 ws: B[k][key], 8 x uint4
        const u16* kp0 = Kp + (bN + k0 + n) * 128 + quad * 8;
        fx4 S0 = {0.f, 0.f, 0.f, 0.f}, S1 = {0.f, 0.f, 0.f, 0.f};
#pragma unroll
        for (int kk = 0; kk < 4; ++kk) {
            bf16x8 kb0 = __builtin_bit_cast(bf16x8, *(const uint4*)(kp0 + kk * 32));
            bf16x8 kb1 = __builtin_bit_cast(bf16x8, *(const uint4*)(kp0 + 16 * 128 + kk * 32));
            S0 = MFMA16(qf[kk], kb0, S0);
            S1 = MFMA16(qf[kk], kb1, S1);
        }

        // ---- online softmax over this 32-key tile
        float alpha[4];
#pragma unroll
        for (int r = 0; r < 4; ++r) {
            const float s0 = S0[r] * SCALE + (a0[r] ? 0.f : -10000.f);
            const float s1 = S1[r] * SCALE + (a1[r] ? 0.f : -10000.f);
            float x = fmaxf(s0, s1);
#pragma unroll
            for (int off = 1; off < 16; off <<= 1) x = fmaxf(x, __shfl_xor(x, off));
            const float mn = fmaxf(m_r[r], x);
            alpha[r] = __expf(m_r[r] - mn);
            m_r[r] = mn;
            const float p0 = __expf(s0 - mn);
            const float p1 = __expf(s1 - mn);
            const u16 ub0 = f2bf(p0), ub1 = f2bf(p1);
            pw[(quad * 4 + r) * 40 + n]      = ub0;
            pw[(quad * 4 + r) * 40 + 16 + n] = ub1;
            float ps = bfbits2f(ub0) + bfbits2f(ub1);
#pragma unroll
            for (int off = 1; off < 16; off <<= 1) ps += __shfl_xor(ps, off);
            l_r[r] = l_r[r] * alpha[r] + ps;
        }
#pragma unroll
        for (int i = 0; i < 8; ++i) {
#pragma unroll
            for (int r = 0; r < 4; ++r) O[i][r] *= alpha[r];
        }

        WAVE_LDS_SYNC();   // pl write -> read, wave-private
        bf16x8 pf = __builtin_bit_cast(bf16x8, *(const uint4*)&pw[n * 40 + quad * 8]);

        // ---- V fragments straight from L2 ws: B[k][d] = vT[d][k], 8 x uint4
        const u16* vp = vTb + k0;
#pragma unroll
        for (int dt = 0; dt < 8; ++dt) {
            bf16x8 vf = __builtin_bit_cast(bf16x8, *(const uint4*)(vp + dt * 32768));
            O[dt] = MFMA16(pf, vf, O[dt]);
        }
    }

    // ---- 4-way merge across key-quarters (one barrier), ELU, store
#pragma unroll
    for (int r = 0; r < 4; ++r) {
        const int row = quad * 4 + r;
        if (n == 0) { mml[h][row] = m_r[r]; mml[h][16 + row] = l_r[r]; }
#pragma unroll
        for (int dt = 0; dt < 8; ++dt)
            mO[h][row * 128 + dt * 16 + n] = O[dt][r];
    }
    __syncthreads();

#pragma unroll
    for (int r = 0; r < 4; ++r) {
        const int row = quad * 4 + r;
        float mh[4], lh[4];
#pragma unroll
        for (int g = 0; g < 4; ++g) { mh[g] = mml[g][row]; lh[g] = mml[g][16 + row]; }
        const float M = fmaxf(fmaxf(mh[0], mh[1]), fmaxf(mh[2], mh[3]));
        float sc[4], L = 0.f;
#pragma unroll
        for (int g = 0; g < 4; ++g) { sc[g] = __expf(mh[g] - M); L += sc[g] * lh[g]; }
        const float linv = 1.f / L;
        float* po = out + (bN + q0 + row) * 128;
#pragma unroll
        for (int dti = 0; dti < 2; ++dti) {
            const int dt = h * 2 + dti;
            float o = 0.f;
#pragma unroll
            for (int g = 0; g < 4; ++g) o += sc[g] * mO[g][row * 128 + dt * 16 + n];
            const float hh = o * linv;
            po[dt * 16 + n] = (hh > 0.f) ? hh : (__expf(hh) - 1.f);
        }
    }
}

// ---------------------------------------------------------------------------
extern "C" void kernel_launch(void* const* d_in, const int* in_sizes, int n_in,
                              void* d_out, int out_size, void* d_ws, size_t ws_size,
                              hipStream_t stream) {
    (void)in_sizes; (void)n_in; (void)out_size; (void)ws_size;
    const float* X   = (const float*)d_in[0];
    const int*   adj = (const int*)d_in[1];
    const float* Wq  = (const float*)d_in[2];
    const float* bq  = (const float*)d_in[3];
    const float* Wk  = (const float*)d_in[4];
    const float* bk  = (const float*)d_in[5];
    const float* Wv  = (const float*)d_in[6];
    const float* bv  = (const float*)d_in[7];
    float* out = (float*)d_out;

    u16* WT   = (u16*)d_out;                     // 96 KB scratch, overwritten by attn
    u16* qws  = (u16*)d_ws;                      // 4 MB  [b*2048+key][d]
    u16* kws  = qws + (size_t)16384 * 128;       // 4 MB  [b*2048+key][d]
    u16* vtws = kws + (size_t)16384 * 128;       // 4 MB  [b][d][key]

    wt_kernel<<<192, 256, 0, stream>>>(Wq, Wk, Wv, WT);
    qkv_kernel<<<512, 256, 0, stream>>>(X, WT, bq, bk, bv, qws, kws, vtws);
    attn_kernel<<<1024, 256, 0, stream>>>(qws, kws, vtws, adj, out);
}

// Round 5
// 269.995 us; speedup vs baseline: 1.3519x; 1.1995x over previous
//
#include <hip/hip_runtime.h>

typedef unsigned short u16;
typedef __bf16 bf16x8 __attribute__((ext_vector_type(8)));
typedef float  fx4    __attribute__((ext_vector_type(4)));

__device__ __forceinline__ u16 f2bf(float f) {
    unsigned int x = __builtin_bit_cast(unsigned int, f);
    x = x + 0x7fffu + ((x >> 16) & 1u);   // round-to-nearest-even
    return (u16)(x >> 16);
}
__device__ __forceinline__ __bf16 f2bf16(float f) {
    return __builtin_bit_cast(__bf16, f2bf(f));
}
__device__ __forceinline__ float bfbits2f(u16 u) {
    unsigned int x = ((unsigned int)u) << 16;
    return __builtin_bit_cast(float, x);
}

#define MFMA16(a, b, c) __builtin_amdgcn_mfma_f32_16x16x32_bf16((a), (b), (c), 0, 0, 0)
// wave-private LDS write->read ordering (DS ops are in-order per wave)
#define WAVE_LDS_SYNC() __asm__ volatile("s_waitcnt lgkmcnt(0)" ::: "memory")

// ---------------------------------------------------------------------------
// Kernel A: WT[p][c][k] = bf16(W_p[k][c])  -> stored in first 96 KB of d_out
// ---------------------------------------------------------------------------
__global__ __launch_bounds__(256) void wt_kernel(
    const float* __restrict__ Wq, const float* __restrict__ Wk,
    const float* __restrict__ Wv, u16* __restrict__ WT)
{
    const int o = blockIdx.x * 256 + threadIdx.x;     // 0..49151
    const int p = o >> 14, rem = o & 16383, c = rem >> 7, k = rem & 127;
    const float* W = (p == 0) ? Wq : ((p == 1) ? Wk : Wv);
    WT[o] = f2bf(W[k * 128 + c]);
}

// ---------------------------------------------------------------------------
// Kernel B: computes Q, K, V^T and stores them FRAGMENT-MAJOR so the attn
// kernel's MFMA fragment loads are single fully-coalesced uint4 loads:
//   Qf[b][qt(128)][kk(4)][lane(64)][j(8)]           (4 KB per q-tile)
//   Kf[b][t(64)][kb(2)][kk(4)][lane(64)][j(8)]      (8 KB per 32-key tile)
//   Vf[b][t(64)][dt(8)][lane(64)][j(8)]             (8 KB per 32-key tile)
// 512 blocks x 256 thr; wave = (row-tile of 16, col/d half of 64).
// ---------------------------------------------------------------------------
__global__ __launch_bounds__(256, 2) void qkv_kernel(
    const float* __restrict__ X, const u16* __restrict__ WT,
    const float* __restrict__ bq, const float* __restrict__ bk,
    const float* __restrict__ bv,
    u16* __restrict__ Qf, u16* __restrict__ Kf, u16* __restrict__ Vf)
{
    const int tid  = threadIdx.x;
    const int w    = tid >> 6;
    const int lane = tid & 63;
    const int n    = lane & 15;
    const int quad = lane >> 4;
    const int gw   = blockIdx.x * 4 + w;   // 0..2047
    const int rt   = gw >> 1, ch = gw & 1;
    const int row0 = rt * 16;
    const int b    = row0 >> 11;
    const int keyb = row0 & 2047;          // multiple of 16

    // X fragments: lane holds X[row0+n][kk*32 + quad*8 + j]  (fp32 -> bf16).
    bf16x8 af[4];
    {
        const float* xr = X + (size_t)(row0 + n) * 128;
#pragma unroll
        for (int kk = 0; kk < 4; ++kk) {
            float4 f0 = *(const float4*)(xr + kk * 32 + quad * 8);
            float4 f1 = *(const float4*)(xr + kk * 32 + quad * 8 + 4);
            bf16x8 a;
            a[0] = f2bf16(f0.x); a[1] = f2bf16(f0.y); a[2] = f2bf16(f0.z); a[3] = f2bf16(f0.w);
            a[4] = f2bf16(f1.x); a[5] = f2bf16(f1.y); a[6] = f2bf16(f1.z); a[7] = f2bf16(f1.w);
            af[kk] = a;
        }
    }

    // ---- Q and K
    const float* Bs[2] = {bq, bk};
#pragma unroll
    for (int p = 0; p < 2; ++p) {
        const u16* wt = WT + p * 16384;
#pragma unroll
        for (int nt = 0; nt < 4; ++nt) {
            const int col0 = ch * 64 + nt * 16;
            fx4 acc = {0.f, 0.f, 0.f, 0.f};
#pragma unroll
            for (int kk = 0; kk < 4; ++kk) {
                bf16x8 bf = __builtin_bit_cast(bf16x8,
                    *(const uint4*)&wt[(col0 + n) * 128 + kk * 32 + quad * 8]);
                acc = MFMA16(af[kk], bf, acc);
            }
            const float bb = Bs[p][col0 + n];
            // element (key = keyb + quad*4 + r, c = col0 + n)
            const int c = col0 + n;
            const int kk_s = c >> 5, quad_s = (c >> 3) & 3, j = c & 7;
            u16* dst;
            if (p == 0) {
                dst = Qf + (((size_t)(b * 128 + (keyb >> 4)) * 4 + kk_s) << 9)
                         + quad_s * 128 + j;
            } else {
                dst = Kf + (((size_t)((b * 64 + (keyb >> 5)) * 2 + ((keyb >> 4) & 1)) * 4 + kk_s) << 9)
                         + quad_s * 128 + j;
            }
#pragma unroll
            for (int r = 0; r < 4; ++r)
                dst[(quad * 4 + r) * 8] = f2bf(acc[r] + bb);
        }
    }

    // ---- V^T[d][key] = sum_k Wv^T[d][k] * X^T[k][key]  (operand-swapped MFMA)
    {
        const u16* wtv = WT + 2 * 16384;
        const int key = keyb + n;                         // C col = n = key offset
        const int t = key >> 5, quad_v = (key >> 3) & 3, jv = key & 7;
#pragma unroll
        for (int d0 = 0; d0 < 4; ++d0) {
            const int dbase = ch * 64 + d0 * 16;
            fx4 acc = {0.f, 0.f, 0.f, 0.f};
#pragma unroll
            for (int kk = 0; kk < 4; ++kk) {
                // A[m=d][k]: lane m=n reads Wv^T row (dbase+n)
                bf16x8 wf = __builtin_bit_cast(bf16x8,
                    *(const uint4*)&wtv[(dbase + n) * 128 + kk * 32 + quad * 8]);
                acc = MFMA16(wf, af[kk], acc);
            }
            // element (d = dbase + quad*4 + r, key)
            u16* dv = Vf + (((size_t)(b * 64 + t) * 8 + (dbase >> 4)) << 9)
                         + quad_v * 128 + jv;
#pragma unroll
            for (int r = 0; r < 4; ++r)
                dv[(quad * 4 + r) * 8] = f2bf(acc[r] + bv[dbase + quad * 4 + r]);
        }
    }
}

// ---------------------------------------------------------------------------
// Kernel C: fused masked attention, NO in-loop barriers, fragment-major loads.
// 1024 blocks (128 q-tiles x 8 batches, b = blockIdx&7 for XCD pinning).
// 4 waves = 4 key-quarters of one 16-query tile; every K/V MFMA fragment is a
// single coalesced uint4 load (base + lane*16B) from L2-resident workspace.
// ---------------------------------------------------------------------------
__global__ __launch_bounds__(256, 4) void attn_kernel(
    const u16* __restrict__ Qf, const u16* __restrict__ Kf,
    const u16* __restrict__ Vf, const int* __restrict__ adj,
    float* __restrict__ out)
{
    __shared__ __align__(16) float mO[4][16 * 128];  // per-wave O dump (32 KB)
    __shared__ __align__(16) float mml[4][32];       // per-wave m[16], l[16]
    __shared__ __align__(16) u16 pl[4][640];         // per-wave P, stride 40

    const int tid  = threadIdx.x;
    const int h    = tid >> 6;                       // key-quarter
    const int lane = tid & 63;
    const int n    = lane & 15;
    const int quad = lane >> 4;
    const int b    = blockIdx.x & 7;
    const int qt   = blockIdx.x >> 3;                // 0..127
    const int q0   = qt * 16;
    const size_t bN = (size_t)b * 2048;

    // Q fragments (A-layout): 4 coalesced 1 KB loads
    bf16x8 qf[4];
    {
        const u16* qp = Qf + ((size_t)(b * 128 + qt) << 11) + lane * 8;
#pragma unroll
        for (int kk = 0; kk < 4; ++kk)
            qf[kk] = __builtin_bit_cast(bf16x8, *(const uint4*)(qp + (kk << 9)));
    }
    const u16* Kb = Kf + ((size_t)b << 18);
    const u16* Vb = Vf + ((size_t)b << 18);

    fx4 O[8];
#pragma unroll
    for (int i = 0; i < 8; ++i) O[i] = (fx4){0.f, 0.f, 0.f, 0.f};
    float m_r[4] = {-1e30f, -1e30f, -1e30f, -1e30f};
    float l_r[4] = {0.f, 0.f, 0.f, 0.f};

    const int* adjb = adj + (bN + q0 + quad * 4) * 2048;
    const float SCALE = 0.08838834764831845f;  // 1/sqrt(128)
    u16* pw = pl[h];

    // prologue: adj for first tile of this quarter
    int a0c[4], a1c[4];
    {
        const int k0 = h * 512;
#pragma unroll
        for (int r = 0; r < 4; ++r) {
            a0c[r] = adjb[(size_t)r * 2048 + k0 + n];
            a1c[r] = adjb[(size_t)r * 2048 + k0 + 16 + n];
        }
    }

    for (int t = 0; t < 16; ++t) {
        const int tg = h * 16 + t;
        const u16* kt_ = Kb + ((size_t)tg << 12) + lane * 8;
        const u16* vt_ = Vb + ((size_t)tg << 12) + lane * 8;

        // ---- prefetch next tile's adjacency into registers
        int a0n[4], a1n[4];
        if (t < 15) {
            const int kn = h * 512 + (t + 1) * 32;
#pragma unroll
            for (int r = 0; r < 4; ++r) {
                a0n[r] = adjb[(size_t)r * 2048 + kn + n];
                a1n[r] = adjb[(size_t)r * 2048 + kn + 16 + n];
            }
        }

        // ---- S = Q K^T : 8 coalesced fragment loads + 8 MFMA
        fx4 S0 = {0.f, 0.f, 0.f, 0.f}, S1 = {0.f, 0.f, 0.f, 0.f};
#pragma unroll
        for (int kk = 0; kk < 4; ++kk) {
            bf16x8 kb0 = __builtin_bit_cast(bf16x8, *(const uint4*)(kt_ + (kk << 9)));
            bf16x8 kb1 = __builtin_bit_cast(bf16x8, *(const uint4*)(kt_ + ((4 + kk) << 9)));
            S0 = MFMA16(qf[kk], kb0, S0);
            S1 = MFMA16(qf[kk], kb1, S1);
        }

        // ---- online softmax over this 32-key tile
        float alpha[4];
#pragma unroll
        for (int r = 0; r < 4; ++r) {
            const float s0 = S0[r] * SCALE + (a0c[r] ? 0.f : -10000.f);
            const float s1 = S1[r] * SCALE + (a1c[r] ? 0.f : -10000.f);
            float x = fmaxf(s0, s1);
#pragma unroll
            for (int off = 1; off < 16; off <<= 1) x = fmaxf(x, __shfl_xor(x, off));
            const float mn = fmaxf(m_r[r], x);
            alpha[r] = __expf(m_r[r] - mn);
            m_r[r] = mn;
            const float p0 = __expf(s0 - mn);
            const float p1 = __expf(s1 - mn);
            const u16 ub0 = f2bf(p0), ub1 = f2bf(p1);
            pw[(quad * 4 + r) * 40 + n]      = ub0;
            pw[(quad * 4 + r) * 40 + 16 + n] = ub1;
            float ps = bfbits2f(ub0) + bfbits2f(ub1);
#pragma unroll
            for (int off = 1; off < 16; off <<= 1) ps += __shfl_xor(ps, off);
            l_r[r] = l_r[r] * alpha[r] + ps;
        }
#pragma unroll
        for (int i = 0; i < 8; ++i) {
#pragma unroll
            for (int r = 0; r < 4; ++r) O[i][r] *= alpha[r];
        }

        WAVE_LDS_SYNC();   // pl write -> read, wave-private
        bf16x8 pf = __builtin_bit_cast(bf16x8, *(const uint4*)&pw[n * 40 + quad * 8]);

        // ---- O += P V : 8 coalesced fragment loads + 8 MFMA
#pragma unroll
        for (int dt = 0; dt < 8; ++dt) {
            bf16x8 vf = __builtin_bit_cast(bf16x8, *(const uint4*)(vt_ + (dt << 9)));
            O[dt] = MFMA16(pf, vf, O[dt]);
        }

#pragma unroll
        for (int r = 0; r < 4; ++r) { a0c[r] = a0n[r]; a1c[r] = a1n[r]; }
    }

    // ---- 4-way merge across key-quarters (one barrier), ELU, store
#pragma unroll
    for (int r = 0; r < 4; ++r) {
        const int row = quad * 4 + r;
        if (n == 0) { mml[h][row] = m_r[r]; mml[h][16 + row] = l_r[r]; }
#pragma unroll
        for (int dt = 0; dt < 8; ++dt)
            mO[h][row * 128 + dt * 16 + n] = O[dt][r];
    }
    __syncthreads();

#pragma unroll
    for (int r = 0; r < 4; ++r) {
        const int row = quad * 4 + r;
        float mh[4], lh[4];
#pragma unroll
        for (int g = 0; g < 4; ++g) { mh[g] = mml[g][row]; lh[g] = mml[g][16 + row]; }
        const float M = fmaxf(fmaxf(mh[0], mh[1]), fmaxf(mh[2], mh[3]));
        float sc[4], L = 0.f;
#pragma unroll
        for (int g = 0; g < 4; ++g) { sc[g] = __expf(mh[g] - M); L += sc[g] * lh[g]; }
        const float linv = 1.f / L;
        float* po = out + (bN + q0 + row) * 128;
#pragma unroll
        for (int dti = 0; dti < 2; ++dti) {
            const int dt = h * 2 + dti;
            float o = 0.f;
#pragma unroll
            for (int g = 0; g < 4; ++g) o += sc[g] * mO[g][row * 128 + dt * 16 + n];
            const float hh = o * linv;
            po[dt * 16 + n] = (hh > 0.f) ? hh : (__expf(hh) - 1.f);
        }
    }
}

// ---------------------------------------------------------------------------
extern "C" void kernel_launch(void* const* d_in, const int* in_sizes, int n_in,
                              void* d_out, int out_size, void* d_ws, size_t ws_size,
                              hipStream_t stream) {
    (void)in_sizes; (void)n_in; (void)out_size; (void)ws_size;
    const float* X   = (const float*)d_in[0];
    const int*   adj = (const int*)d_in[1];
    const float* Wq  = (const float*)d_in[2];
    const float* bq  = (const float*)d_in[3];
    const float* Wk  = (const float*)d_in[4];
    const float* bk  = (const float*)d_in[5];
    const float* Wv  = (const float*)d_in[6];
    const float* bv  = (const float*)d_in[7];
    float* out = (float*)d_out;

    u16* WT  = (u16*)d_out;                      // 96 KB scratch, overwritten by attn
    u16* Qf  = (u16*)d_ws;                       // 4 MB fragment-major Q
    u16* Kf  = Qf + (size_t)16384 * 128;         // 4 MB fragment-major K
    u16* Vf  = Kf + (size_t)16384 * 128;         // 4 MB fragment-major V^T

    wt_kernel<<<192, 256, 0, stream>>>(Wq, Wk, Wv, WT);
    qkv_kernel<<<512, 256, 0, stream>>>(X, WT, bq, bk, bv, Qf, Kf, Vf);
    attn_kernel<<<1024, 256, 0, stream>>>(Qf, Kf, Vf, adj, out);
}